// Round 7
// baseline (248.416 us; speedup 1.0000x reference)
//
#include <hip/hip_runtime.h>
#include <stdint.h>

typedef __attribute__((ext_vector_type(8))) short short8;
typedef __attribute__((ext_vector_type(4))) float f32x4;

#define S_LEN 2048
#define HID 2048
#define NH 16
#define NKV 4
#define DH 128
#define WINDOW 1024
// SCALE * log2(e): scores produced directly in exp2 domain
#define SCALE2 0.12751744f

__device__ __forceinline__ unsigned short f2bf(float f) {
    unsigned int u = __float_as_uint(f);
    unsigned int r = (u + 0x7fffu + ((u >> 16) & 1u)) >> 16;
    return (unsigned short)r;
}

__device__ __forceinline__ void gload16(const void* g, void* l) {
    __builtin_amdgcn_global_load_lds((__attribute__((address_space(1))) void*)g,
                                     (__attribute__((address_space(3))) void*)l, 16, 0, 0);
}

// ---------------- fused prep kernel ----------------
// grid partition:
// [0,2048)      cast hs f32 -> bf16 (short8 granules)
// [2048,2560)   rope cos/sin tables [2048][64] f32
// [2560,2572)   bias concat
// [2572,3596)   transpose Wq  (32 x 32 tiles of 64)
// [3596,3852)   transpose Wk  (8 x 32)
// [3852,4108)   transpose Wv  (8 x 32)
// [4108,5132)   transpose Wo  (32 x 32)

__device__ __forceinline__ void tile_t64(const float* __restrict__ src,
                                         unsigned short* __restrict__ dst,
                                         int N, int K, int rowoff, int idx, int nbx,
                                         unsigned short* t /*64*72*/) {
    const int nx = idx % nbx, ky = idx / nbx;
    const int n0 = nx * 64, k0 = ky * 64;
    const int tid = threadIdx.x;
    // phase 1: coalesced float4 reads, swizzled LDS store
#pragma unroll
    for (int it = 0; it < 4; it++) {
        const int id = it * 256 + tid;
        const int k = id >> 4, nc = (id & 15) * 4;
        float4 v = *(const float4*)(src + (size_t)(k0 + k) * N + n0 + nc);
        ushort4 o;
        o.x = f2bf(v.x); o.y = f2bf(v.y); o.z = f2bf(v.z); o.w = f2bf(v.w);
        *(ushort4*)&t[k * 72 + (nc ^ ((k >> 3) << 3))] = o;
    }
    __syncthreads();
    // phase 2: gather columns from LDS, coalesced short8 writes
#pragma unroll
    for (int it = 0; it < 2; it++) {
        const int id = it * 256 + tid;
        const int n = id >> 3, kc = (id & 7) * 8;
        const int cswz = n ^ ((id & 7) << 3);
        short8 v;
#pragma unroll
        for (int j = 0; j < 8; j++) v[j] = (short)t[(kc + j) * 72 + cswz];
        *(short8*)(dst + (size_t)(rowoff + n0 + n) * K + k0 + kc) = v;
    }
}

__global__ __launch_bounds__(256) void prep_kernel(
    const float* __restrict__ hs, unsigned short* __restrict__ hsb,
    const float* __restrict__ bq, const float* __restrict__ bk, const float* __restrict__ bv,
    float* __restrict__ cbias, float* __restrict__ cst, float* __restrict__ snt,
    const float* __restrict__ Wq, const float* __restrict__ Wk,
    const float* __restrict__ Wv, const float* __restrict__ Wo,
    unsigned short* __restrict__ wqkvT, unsigned short* __restrict__ woT) {
    __shared__ unsigned short t[64 * 72];
    const int b = blockIdx.x, tid = threadIdx.x;
    if (b < 2048) {
        const int i = b * 256 + tid;
        float4 v0 = ((const float4*)hs)[i * 2];
        float4 v1 = ((const float4*)hs)[i * 2 + 1];
        short8 o;
        o[0] = f2bf(v0.x); o[1] = f2bf(v0.y); o[2] = f2bf(v0.z); o[3] = f2bf(v0.w);
        o[4] = f2bf(v1.x); o[5] = f2bf(v1.y); o[6] = f2bf(v1.z); o[7] = f2bf(v1.w);
        ((short8*)hsb)[i] = o;
    } else if (b < 2560) {
        const int idx = (b - 2048) * 256 + tid;
        const int s = idx >> 6, f = idx & 63;
        float inv = __expf(-(float)f * (logf(10000.f) / 64.f));
        float ang = (float)s * inv;
        float si, co;
        sincosf(ang, &si, &co);
        cst[idx] = co;
        snt[idx] = si;
    } else if (b < 2572) {
        const int i = (b - 2560) * 256 + tid;
        if (i < 3072) {
            float v;
            if (i < 2048) v = bq[i];
            else if (i < 2560) v = bk[i - 2048];
            else v = bv[i - 2560];
            cbias[i] = v;
        }
    } else if (b < 3596) {
        tile_t64(Wq, wqkvT, 2048, 2048, 0, b - 2572, 32, t);
    } else if (b < 3852) {
        tile_t64(Wk, wqkvT, 512, 2048, 2048, b - 3596, 8, t);
    } else if (b < 4108) {
        tile_t64(Wv, wqkvT, 512, 2048, 2560, b - 3852, 8, t);
    } else {
        tile_t64(Wo, woT, 2048, 2048, 0, b - 4108, 32, t);
    }
}

// ---------------- GEMM: C[M,N] = A[M,K] * Bt[N,K]^T (+bias) ----------------
// 128x128 tile, BK=32, triple-buffered LDS, depth-2 global_load_lds prefetch,
// counted vmcnt, both-sides chunk swizzle, setprio. Waves own 32-row slabs
// (acc[2][8]) so the RoPE partner col d^64 is acc[m][n^4] in the SAME lane.
// EPI: 0 = plain f32 C, 1 = fused RoPE + Qr/Kr/Vt layout epilogue.

template <int EPI>
__global__ __launch_bounds__(256) void gemm_pipe(
    const unsigned short* __restrict__ A, const unsigned short* __restrict__ Bt,
    float* __restrict__ C, const float* __restrict__ bias, int M, int N, int K,
    unsigned short* __restrict__ Qr, unsigned short* __restrict__ Kr,
    unsigned short* __restrict__ Vt,
    const float* __restrict__ cst, const float* __restrict__ snt) {
    __shared__ unsigned short Al[3][128 * 32];
    __shared__ unsigned short Bl[3][128 * 32];
    const int tid = threadIdx.x, lane = tid & 63, w = tid >> 6;
    const int lo = lane & 15, hi = lane >> 4;
    const int nbn = N >> 7;
    const int nwg8 = gridDim.x >> 3;
    const int wg = (blockIdx.x & 7) * nwg8 + (blockIdx.x >> 3);
    const int bm = wg / nbn, bn = wg % nbn;
    const int m0 = bm << 7, n0 = bn << 7;
    const size_t Kb = (size_t)K * 2;

    const char* Ab = (const char*)A + (size_t)m0 * Kb;
    const char* Bb = (const char*)Bt + (size_t)n0 * Kb;
    char* Alb = (char*)&Al[0][0];
    char* Blb = (char*)&Bl[0][0];

    const int L0 = tid * 16;
    const int L1 = 4096 + tid * 16;
    const int r0 = L0 >> 6, r1 = L1 >> 6;
    const size_t go0 = (size_t)r0 * Kb + ((((L0 >> 4) & 3) ^ (r0 & 3)) << 4);
    const size_t go1 = (size_t)r1 * Kb + ((((L1 >> 4) & 3) ^ (r1 & 3)) << 4);

    auto stage = [&](int buf, int kt) {
        const char* Ak = Ab + (size_t)kt * 64;
        const char* Bk = Bb + (size_t)kt * 64;
        char* Ad = Alb + buf * 8192;
        char* Bd = Blb + buf * 8192;
        gload16(Ak + go0, Ad + L0);
        gload16(Ak + go1, Ad + L1);
        gload16(Bk + go0, Bd + L0);
        gload16(Bk + go1, Bd + L1);
    };

    f32x4 acc[2][8] = {};
    const int NT = K >> 5;
    const int swz = (hi ^ (lo & 3)) << 4;

    stage(0, 0);
    stage(1, 1);
    int buf = 0, nstage = 2;
    for (int kt = 0; kt < NT; ++kt) {
        if (kt < NT - 1)
            asm volatile("s_waitcnt vmcnt(4)" ::: "memory");
        else
            asm volatile("s_waitcnt vmcnt(0)" ::: "memory");
        __builtin_amdgcn_s_barrier();

        const char* Ar = Alb + buf * 8192;
        const char* Br = Blb + buf * 8192;
        short8 af[2], bfr[8];
#pragma unroll
        for (int m = 0; m < 2; m++)
            af[m] = *(const short8*)(Ar + (w * 32 + m * 16 + lo) * 64 + swz);
#pragma unroll
        for (int n = 0; n < 8; n++)
            bfr[n] = *(const short8*)(Br + (n * 16 + lo) * 64 + swz);
        asm volatile("s_waitcnt lgkmcnt(0)" ::: "memory");
        __builtin_amdgcn_s_barrier();

        if (kt + 2 < NT) {
            int bst = nstage;
            bst = (bst >= 3) ? bst - 3 : bst;
            stage(bst, kt + 2);
            nstage = bst + 1;
        }
        __builtin_amdgcn_sched_barrier(0);

        __builtin_amdgcn_s_setprio(1);
#pragma unroll
        for (int m = 0; m < 2; m++)
#pragma unroll
            for (int n = 0; n < 8; n++)
                acc[m][n] = __builtin_amdgcn_mfma_f32_16x16x32_bf16(af[m], bfr[n], acc[m][n], 0, 0, 0);
        __builtin_amdgcn_s_setprio(0);

        buf = (buf == 2) ? 0 : buf + 1;
    }

    const int sbase = m0 + w * 32 + hi * 4;
    if constexpr (EPI == 0) {
#pragma unroll
        for (int m = 0; m < 2; m++) {
            const int row = sbase + m * 16;
#pragma unroll
            for (int n = 0; n < 8; n++) {
                const int col = n0 + n * 16 + lo;
                const float badd = bias ? bias[col] : 0.f;
#pragma unroll
                for (int r = 0; r < 4; r++)
                    C[(size_t)(row + r) * N + col] = acc[m][n][r] + badd;
            }
        }
    } else {
        if (bn < 20) {
            float csv[2][4][4], snv[2][4][4];
#pragma unroll
            for (int m = 0; m < 2; m++)
#pragma unroll
                for (int r = 0; r < 4; r++) {
                    const int s = sbase + m * 16 + r;
#pragma unroll
                    for (int fi = 0; fi < 4; fi++) {
                        const int f = fi * 16 + lo;
                        csv[m][r][fi] = cst[s * 64 + f];
                        snv[m][r][fi] = snt[s * 64 + f];
                    }
                }
            unsigned short* dst = (bn < 16) ? (Qr + (size_t)bn * S_LEN * 128)
                                            : (Kr + (size_t)(bn - 16) * S_LEN * 128);
#pragma unroll
            for (int m = 0; m < 2; m++) {
#pragma unroll
                for (int n = 0; n < 8; n++) {
                    const int d = n * 16 + lo;
                    const float badd = bias[n0 + d];
                    const float badd2 = bias[n0 + (d ^ 64)];
#pragma unroll
                    for (int r = 0; r < 4; r++) {
                        const float x = acc[m][n][r] + badd;
                        const float y = acc[m][n ^ 4][r] + badd2;
                        const float cs = csv[m][r][n & 3];
                        const float sn = snv[m][r][n & 3];
                        const float out = (n < 4) ? x * cs - y * sn : x * cs + y * sn;
                        const int s = sbase + m * 16 + r;
                        dst[(size_t)s * 128 + d] = f2bf(out);
                    }
                }
            }
        } else {
            const int kvh = bn - 20;
#pragma unroll
            for (int m = 0; m < 2; m++) {
                const int s0r = sbase + m * 16;
#pragma unroll
                for (int n = 0; n < 8; n++) {
                    const int d = n * 16 + lo;
                    const float badd = bias[n0 + d];
                    ushort4 pk;
                    pk.x = f2bf(acc[m][n][0] + badd);
                    pk.y = f2bf(acc[m][n][1] + badd);
                    pk.z = f2bf(acc[m][n][2] + badd);
                    pk.w = f2bf(acc[m][n][3] + badd);
                    *(ushort4*)(Vt + (size_t)(kvh * 128 + d) * S_LEN + s0r) = pk;
                }
            }
        }
    }
}

// ---------------- flash attention, sliding window, GQA, split-KV ----------------
// blockIdx.z halves the kt range; partials (O, m, l) in exp2 domain merged later.

__global__ __launch_bounds__(256) void attn_kernel(const unsigned short* __restrict__ Qr,
                                                   const unsigned short* __restrict__ Kr,
                                                   const unsigned short* __restrict__ Vt,
                                                   float* __restrict__ Op,
                                                   float2* __restrict__ mlb) {
    __shared__ unsigned short Kl[2][64 * 128];
    __shared__ unsigned short Vl[2][128 * 64];
    __shared__ unsigned short Pl[4][16 * 64];
    const int tid = threadIdx.x, lane = tid & 63, w = tid >> 6;
    const int h = blockIdx.y, qt = blockIdx.x, z = blockIdx.z;
    const int kvh = h >> 2;
    const int q0 = qt * 64;
    const int lo = lane & 15, hi = lane >> 4;

    // split-KV tile range
    const int t0f = (q0 >= 1023) ? (q0 - 1023) >> 6 : 0;
    const int T = qt - t0f + 1;
    const int half = T >> 1;
    const int tb = z ? t0f + half : t0f;
    const int te = z ? qt : t0f + half - 1;  // inclusive
    const int zh = z * 16 + h;

    if (te < tb) {
        // empty half: record (m=-inf, l=0); O never read (coef 0)
        if (lo == 0) {
#pragma unroll
            for (int r = 0; r < 4; r++) {
                const int s = q0 + w * 16 + hi * 4 + r;
                mlb[(size_t)zh * S_LEN + s] = make_float2(-INFINITY, 0.f);
            }
        }
        return;
    }

    const unsigned short* Qb =
        Qr + ((size_t)h * S_LEN + q0 + w * 16 + lo) * 128 + hi * 8;
    short8 qf[4];
#pragma unroll
    for (int ks = 0; ks < 4; ++ks) qf[ks] = *(const short8*)(Qb + ks * 32);

    const short8 ones = {16256, 16256, 16256, 16256, 16256, 16256, 16256, 16256};

    float mrow[4] = {-INFINITY, -INFINITY, -INFINITY, -INFINITY};
    f32x4 o[8] = {};
    f32x4 ol = {};

    const char* Kg = (const char*)(Kr + (size_t)kvh * S_LEN * 128);
    const char* Vg = (const char*)(Vt + (size_t)kvh * 128 * S_LEN);
    char* Klb = (char*)&Kl[0][0];
    char* Vlb = (char*)&Vl[0][0];
    const int wb = w * 1024;

    auto stage = [&](int buf, int kt) {
        const int k0 = kt * 64;
#pragma unroll
        for (int iss = 0; iss < 4; ++iss) {
            int lin = iss * 4096 + tid * 16;
            int row = lin >> 8;
            int chunk = (lin >> 4) & 15;
            gload16(Kg + (size_t)(k0 + row) * 256 + ((chunk ^ (row & 7)) << 4),
                    Klb + buf * 16384 + iss * 4096 + wb);
            int d = lin >> 7;
            int vchunk = (lin >> 4) & 7;
            gload16(Vg + (size_t)d * (S_LEN * 2) + (size_t)k0 * 2 + ((vchunk ^ (d & 7)) << 4),
                    Vlb + buf * 16384 + iss * 4096 + wb);
        }
    };

    const int qmin = q0 + w * 16;
    stage(0, tb);
    for (int kt = tb; kt <= te; ++kt) {
        __syncthreads();
        if (kt < te) stage((kt - tb + 1) & 1, kt + 1);
        const int buf = (kt - tb) & 1;
        const int k0 = kt * 64;
        const char* Kb = Klb + buf * 16384;
        const char* Vb = Vlb + buf * 16384;

        // QK^T
        f32x4 sc[4];
        __builtin_amdgcn_s_setprio(1);
#pragma unroll
        for (int t = 0; t < 4; t++) {
            sc[t] = (f32x4){0.f, 0.f, 0.f, 0.f};
            const int krow = t * 16 + lo;
#pragma unroll
            for (int ks = 0; ks < 4; ks++) {
                const int chunk = ks * 4 + hi;
                short8 kf = *(const short8*)(Kb + krow * 256 + ((chunk ^ (krow & 7)) << 4));
                sc[t] = __builtin_amdgcn_mfma_f32_16x16x32_bf16(qf[ks], kf, sc[t], 0, 0, 0);
            }
        }
        __builtin_amdgcn_s_setprio(0);

        // scores (exp2 domain) + mask, interior fast path
        const bool full = (k0 + 63 <= qmin) && (k0 >= qmin + 15 - (WINDOW - 1));
        float ps[4][4];
        float mt[4];
        if (full) {
#pragma unroll
            for (int r = 0; r < 4; r++) {
                float m0v = -INFINITY;
#pragma unroll
                for (int t = 0; t < 4; t++) {
                    float sv = sc[t][r] * SCALE2;
                    ps[t][r] = sv;
                    m0v = fmaxf(m0v, sv);
                }
                mt[r] = m0v;
            }
        } else {
#pragma unroll
            for (int r = 0; r < 4; r++) {
                const int q = qmin + hi * 4 + r;
                float m0v = -INFINITY;
#pragma unroll
                for (int t = 0; t < 4; t++) {
                    const int k = k0 + t * 16 + lo;
                    const bool valid = (k <= q) && (q - k < WINDOW);
                    float sv = valid ? sc[t][r] * SCALE2 : -INFINITY;
                    ps[t][r] = sv;
                    m0v = fmaxf(m0v, sv);
                }
                mt[r] = m0v;
            }
        }

        // online max with defer (THR=8 in log2 domain)
        float alpha[4];
        bool need = false;
#pragma unroll
        for (int r = 0; r < 4; r++) {
#pragma unroll
            for (int off = 1; off < 16; off <<= 1) mt[r] = fmaxf(mt[r], __shfl_xor(mt[r], off, 64));
            const float mo = mrow[r];
            const float mn = (mt[r] > mo + 8.f) ? mt[r] : mo;
            const bool resc = (mn != mo);
            alpha[r] = resc ? exp2f(mo - mn) : 1.f;
            need = need || resc;
            mrow[r] = mn;
            const float mn_e = (mn == -INFINITY) ? 0.f : mn;
#pragma unroll
            for (int t = 0; t < 4; t++) ps[t][r] = exp2f(ps[t][r] - mn_e);
        }

        // P -> LDS (bf16, swizzled 128B rows)
        char* Pw = (char*)&Pl[w][0];
#pragma unroll
        for (int r = 0; r < 4; r++) {
            const int prow = hi * 4 + r;
#pragma unroll
            for (int t = 0; t < 4; t++) {
                const int col = t * 16 + lo;
                const int chunk = col >> 3;
                *(unsigned short*)(Pw + prow * 128 + ((chunk ^ (prow & 7)) << 4) + (col & 7) * 2) =
                    f2bf(ps[t][r]);
            }
        }
        asm volatile("s_waitcnt lgkmcnt(0)" ::: "memory");
        __builtin_amdgcn_sched_barrier(0);

        // rescale O and l
        if (__any(need)) {
#pragma unroll
            for (int n = 0; n < 8; n++)
#pragma unroll
                for (int r = 0; r < 4; r++) o[n][r] *= alpha[r];
#pragma unroll
            for (int r = 0; r < 4; r++) ol[r] *= alpha[r];
        }

        // hoisted P fragments
        short8 pa[2];
#pragma unroll
        for (int ks = 0; ks < 2; ++ks) {
            const int chunk = ks * 4 + hi;
            pa[ks] = *(const short8*)(Pw + lo * 128 + ((chunk ^ (lo & 7)) << 4));
        }

        // PV + l accumulation
        __builtin_amdgcn_s_setprio(1);
        ol = __builtin_amdgcn_mfma_f32_16x16x32_bf16(pa[0], ones, ol, 0, 0, 0);
        ol = __builtin_amdgcn_mfma_f32_16x16x32_bf16(pa[1], ones, ol, 0, 0, 0);
#pragma unroll
        for (int n = 0; n < 8; n++) {
            const int d = n * 16 + lo;
#pragma unroll
            for (int ks = 0; ks < 2; ++ks) {
                const int chunk = ks * 4 + hi;
                short8 vbf = *(const short8*)(Vb + d * 128 + ((chunk ^ (d & 7)) << 4));
                o[n] = __builtin_amdgcn_mfma_f32_16x16x32_bf16(pa[ks], vbf, o[n], 0, 0, 0);
            }
        }
        __builtin_amdgcn_s_setprio(0);
        __syncthreads();
    }

    // epilogue: raw partials
    float* Ob = Op + ((size_t)zh * S_LEN + q0 + w * 16) * 128;
#pragma unroll
    for (int r = 0; r < 4; r++) {
        const int sq = hi * 4 + r;
#pragma unroll
        for (int n = 0; n < 8; n++) {
            const int d = n * 16 + lo;
            Ob[(size_t)sq * 128 + d] = o[n][r];
        }
    }
    if (lo == 0) {
#pragma unroll
        for (int r = 0; r < 4; r++) {
            const int s = q0 + w * 16 + hi * 4 + r;
            mlb[(size_t)zh * S_LEN + s] = make_float2(mrow[r], ol[r]);
        }
    }
}

// ---------------- merge partials + gate -> attnb (bf16) ----------------

__global__ __launch_bounds__(256) void merge_kernel(const float* __restrict__ Op,
                                                    const float2* __restrict__ mlb,
                                                    const float* __restrict__ mg,
                                                    unsigned short* __restrict__ attnb) {
    const int s = blockIdx.x;
    const int h = threadIdx.x >> 4;
    const int d0 = (threadIdx.x & 15) * 8;
    const float fac = 1.f - 1.f / (1.f + __expf(-mg[h]));
    const float2 a = mlb[(size_t)h * S_LEN + s];
    const float2 b = mlb[(size_t)(16 + h) * S_LEN + s];
    const float m0 = (a.y > 0.f) ? a.x : -INFINITY;
    const float m1 = (b.y > 0.f) ? b.x : -INFINITY;
    const float ms = fmaxf(m0, m1);
    const float c0 = (a.y > 0.f) ? exp2f(a.x - ms) : 0.f;
    const float c1 = (b.y > 0.f) ? exp2f(b.x - ms) : 0.f;
    const float inv = fac / (c0 * a.y + c1 * b.y);
    const float* O0 = Op + ((size_t)h * S_LEN + s) * 128 + d0;
    const float* O1 = Op + ((size_t)(16 + h) * S_LEN + s) * 128 + d0;
    float4 x0 = *(const float4*)O0, x1 = *(const float4*)(O0 + 4);
    float4 y0 = *(const float4*)O1, y1 = *(const float4*)(O1 + 4);
    short8 out;
    out[0] = f2bf((c0 * x0.x + c1 * y0.x) * inv);
    out[1] = f2bf((c0 * x0.y + c1 * y0.y) * inv);
    out[2] = f2bf((c0 * x0.z + c1 * y0.z) * inv);
    out[3] = f2bf((c0 * x0.w + c1 * y0.w) * inv);
    out[4] = f2bf((c0 * x1.x + c1 * y1.x) * inv);
    out[5] = f2bf((c0 * x1.y + c1 * y1.y) * inv);
    out[6] = f2bf((c0 * x1.z + c1 * y1.z) * inv);
    out[7] = f2bf((c0 * x1.w + c1 * y1.w) * inv);
    *(short8*)(attnb + (size_t)s * 2048 + h * 128 + d0) = out;
}

// ---------------- launch ----------------

extern "C" void kernel_launch(void* const* d_in, const int* in_sizes, int n_in,
                              void* d_out, int out_size, void* d_ws, size_t ws_size,
                              hipStream_t stream) {
    const float* hs = (const float*)d_in[0];
    const float* Wq = (const float*)d_in[1];
    const float* bq = (const float*)d_in[2];
    const float* Wk = (const float*)d_in[3];
    const float* bk = (const float*)d_in[4];
    const float* Wv = (const float*)d_in[5];
    const float* bv = (const float*)d_in[6];
    const float* Wo = (const float*)d_in[7];
    const float* mg = (const float*)d_in[8];

    char* ws = (char*)d_ws;
    // Op (32 MB) overlays hsb+wqkvT (both dead after gemm1)
    float*          Op    = (float*)(ws + 0);                   // 32 MB
    unsigned short* hsb   = (unsigned short*)(ws + 0);          // 8 MB
    unsigned short* wqkvT = (unsigned short*)(ws + 8388608);    // 12 MB
    unsigned short* Qrb   = (unsigned short*)(ws + 33554432);   // 8 MB
    unsigned short* Krb   = (unsigned short*)(ws + 41943040);   // 2 MB
    unsigned short* Vtb   = (unsigned short*)(ws + 44040192);   // 2 MB
    unsigned short* woT   = (unsigned short*)(ws + 46137344);   // 8 MB
    float*          cbias = (float*)(ws + 54525952);            // 12 KB
    float*          cst   = (float*)(ws + 54542336);            // 512 KB
    float*          snt   = (float*)(ws + 55066624);            // 512 KB
    float2*         mlb   = (float2*)(ws + 55590912);           // 512 KB
    unsigned short* attnb = (unsigned short*)(ws + 56623104);   // 8 MB -> end 62 MiB

    // 1. fused prep
    prep_kernel<<<5132, 256, 0, stream>>>(hs, hsb, bq, bk, bv, cbias, cst, snt,
                                          Wq, Wk, Wv, Wo, wqkvT, woT);

    // 2. QKV projection + fused bias/RoPE/layout epilogue
    gemm_pipe<1><<<16 * 24, 256, 0, stream>>>(hsb, wqkvT, nullptr, cbias, 2048, 3072, 2048,
                                              Qrb, Krb, Vtb, cst, snt);

    // 3. attention, split-KV (z = 0/1) -> f32 partials (overwrites hsb/wqkvT region)
    attn_kernel<<<dim3(32, 16, 2), 256, 0, stream>>>(Qrb, Krb, Vtb, Op, mlb);

    // 4. merge partials + gate -> attnb bf16
    merge_kernel<<<2048, 256, 0, stream>>>(Op, mlb, mg, attnb);

    // 5. output projection -> d_out (f32)
    gemm_pipe<0><<<16 * 16, 256, 0, stream>>>(attnb, woT, (float*)d_out, nullptr, 2048, 2048, 2048,
                                              nullptr, nullptr, nullptr, nullptr, nullptr);
}